// Round 10
// baseline (37.720 us; speedup 1.0000x reference)
//
#include <hip/hip_runtime.h>
#include <hip/hip_bf16.h>
#include <math.h>

#define SEQ  1024
#define NH   32

typedef __attribute__((ext_vector_type(8))) short short8_t;
typedef __attribute__((ext_vector_type(4))) short short4_t;
typedef __attribute__((ext_vector_type(4))) float float4_t;

__device__ inline short f2bf(float f) {
    __hip_bfloat16 h = __float2bfloat16(f);
    return *reinterpret_cast<short*>(&h);
}

// Trans-pipe-free exp2: cubic poly on fract(v), exponent via v_ldexp_f32.
// ~6 full-rate VALU inst (fract, cvt_flr, 3 fma, ldexp) vs v_exp_f32's
// 16-32 trans cycles. Max rel err 1.4e-4 (minimax cubic on [0,1)) — far
// inside bf16's 2e-3 half-ulp, and softmax normalization cancels the
// smooth common-mode part.
__device__ inline float exp2_poly(float v) {
#if __has_builtin(__builtin_amdgcn_fractf)
    float f = __builtin_amdgcn_fractf(v);
#else
    float f = v - floorf(v);
#endif
    int   e = (int)floorf(v);                 // fuses to v_cvt_flr_i32_f32
    float p = fmaf(f, fmaf(f, fmaf(f, 0.078024523f, 0.22606716f),
                           0.69583354f), 0.99992522f);
    return ldexpf(p, e);                      // v_ldexp_f32 (range-safe)
}

// Block = 256 threads = 4 waves; each wave owns 32 query rows (two 16-row
// subtiles A/B sharing all LDS reads). grid = B*NH*(SEQ/128) = 1024 blocks
// = 4 blocks/CU resident.
//
// scores^T[t,s] = sum_k x[t,k] * y'[s,k]  (K=4 padded to 32, bf16 MFMA)
//   y'[s] = (x_s Wq) Wk^T * (1/sqrt(8)) * log2(e)
// w = exp2(scores)   (no max subtraction: |score2| << 127, fp32 l can't overflow)
// Z^T[c,s] = sum_t XaugT[c,t] * w^T[t,s]  (Xaug rows: x0..x3, ones -> l, zeros)
// out[s, h*8+j] = (sum_c Z[c,s] Wv[c,j]) / Z[4,s]
__global__ __launch_bounds__(256, 4) void mha_mfma_kernel(
    const float* __restrict__ x,    // [B, SEQ, 4]
    const float* __restrict__ Wq,   // [NH, 4, 8]
    const float* __restrict__ Wk,   // [NH, 4, 8]
    const float* __restrict__ Wv,   // [NH, 4, 8]
    float* __restrict__ out)        // [B, SEQ, NH*8]
{
    const int bid = blockIdx.x;
    const int rc  = bid & 7;            // row chunk (SEQ/128 = 8)
    const int h   = (bid >> 3) & 31;
    const int b   = bid >> 8;

    const int tid  = threadIdx.x;
    const int lane = tid & 63;
    const int wv   = tid >> 6;          // 0..3
    const int l15  = lane & 15;
    const int g    = lane >> 4;

    __shared__ short xbf[SEQ][4];       // 8 KB    row-major bf16 x
    __shared__ short xT[6][1032];       // 12.1 KB rows: x0..x3, ones, zeros

    // ---- stage ----
    const float4* xg = (const float4*)(x + (size_t)b * SEQ * 4);
    for (int i = tid; i < SEQ; i += 256) {
        float4 v = xg[i];
        short s0 = f2bf(v.x), s1 = f2bf(v.y), s2 = f2bf(v.z), s3 = f2bf(v.w);
        short4_t pk = {s0, s1, s2, s3};
        *(short4_t*)(&xbf[i][0]) = pk;
        xT[0][i] = s0; xT[1][i] = s1; xT[2][i] = s2; xT[3][i] = s3;
        xT[4][i] = (short)0x3F80;       // 1.0 bf16 (l-column)
        xT[5][i] = 0;                   // zero row (PV A rows >= 5)
    }

    // ---- per-lane y' for the two subtiles (B-frags of scores MFMA) ----
    const int rowA = rc * 128 + wv * 32 + l15;      // subtile A
    const int rowB = rowA + 16;                     // subtile B
    const float* wqp = Wq + h * 32;     // [4][8]
    const float* wkp = Wk + h * 32;
    const float cs = 0.35355339059327373f * 1.4426950408889634f; // 1/sqrt(8)*log2e

    float4 xsA = xg[rowA];
    float4 xsB = xg[rowB];
    float qA[8], qB[8];
#pragma unroll
    for (int m = 0; m < 8; ++m) {
        qA[m] = xsA.x * wqp[m] + xsA.y * wqp[8 + m] + xsA.z * wqp[16 + m] + xsA.w * wqp[24 + m];
        qB[m] = xsB.x * wqp[m] + xsB.y * wqp[8 + m] + xsB.z * wqp[16 + m] + xsB.w * wqp[24 + m];
    }
    short8_t yA = {0,0,0,0,0,0,0,0};
    short8_t yB = {0,0,0,0,0,0,0,0};
    if (lane < 16) {
#pragma unroll
        for (int i = 0; i < 4; ++i) {
            float ya = 0.f, yb = 0.f;
#pragma unroll
            for (int m = 0; m < 8; ++m) {
                ya += qA[m] * wkp[i * 8 + m];
                yb += qB[m] * wkp[i * 8 + m];
            }
            yA[i] = f2bf(ya * cs);
            yB[i] = f2bf(yb * cs);
        }
    }

    __syncthreads();

    // scores-A: ALL lanes read x rows t0 + f(l15), f = 8*(l>>2)+(l&3)
    // (lanes 16..63 duplicate lanes 0..15's addresses -> LDS broadcast)
    const short* abase = &xbf[8 * (l15 >> 2) + (l15 & 3)][0];
    // PV-A: row c = l15 (c>=5 -> zero row; their Z rows are ignored)
    const int rowm = (l15 < 5) ? l15 : 5;
    const short* vbase = &xT[rowm][8 * g];

    float4_t zA = {0.f, 0.f, 0.f, 0.f};
    float4_t zB = {0.f, 0.f, 0.f, 0.f};
    const float4_t cz = {0.f, 0.f, 0.f, 0.f};

#pragma unroll 4
    for (int it = 0; it < 32; ++it) {
        short4_t a1lo = *(const short4_t*)(abase + it * 128);        // rows f(l15)+32it
        short4_t a2lo = *(const short4_t*)(abase + it * 128 + 16);   // +4 rows
        short8_t a1 = {a1lo[0], a1lo[1], a1lo[2], a1lo[3], 0, 0, 0, 0};
        short8_t a2 = {a2lo[0], a2lo[1], a2lo[2], a2lo[3], 0, 0, 0, 0};
        short8_t av = *(const short8_t*)(vbase + it * 32);           // XaugT[c][32it+8g..]

        float4_t c1A = __builtin_amdgcn_mfma_f32_16x16x32_bf16(a1, yA, cz, 0, 0, 0);
        float4_t c2A = __builtin_amdgcn_mfma_f32_16x16x32_bf16(a2, yA, cz, 0, 0, 0);
        float4_t c1B = __builtin_amdgcn_mfma_f32_16x16x32_bf16(a1, yB, cz, 0, 0, 0);
        float4_t c2B = __builtin_amdgcn_mfma_f32_16x16x32_bf16(a2, yB, cz, 0, 0, 0);

        short8_t wfA, wfB;
#pragma unroll
        for (int i = 0; i < 4; ++i) {
            wfA[i]     = f2bf(exp2_poly(c1A[i]));
            wfA[4 + i] = f2bf(exp2_poly(c2A[i]));
            wfB[i]     = f2bf(exp2_poly(c1B[i]));
            wfB[4 + i] = f2bf(exp2_poly(c2B[i]));
        }

        zA = __builtin_amdgcn_mfma_f32_16x16x32_bf16(av, wfA, zA, 0, 0, 0);
        zB = __builtin_amdgcn_mfma_f32_16x16x32_bf16(av, wfB, zB, 0, 0, 0);
    }

    // ---- epilogue ----
    // C layout: col = lane&15 (s), row = 4*(lane>>4)+reg (c). Need c=0..3 and c=4 (=l).
    float lsA = __shfl(zA[0], 16 + l15);
    float a0  = __shfl(zA[0], l15);
    float a1e = __shfl(zA[1], l15);
    float a2e = __shfl(zA[2], l15);
    float a3e = __shfl(zA[3], l15);
    float lsB = __shfl(zB[0], 16 + l15);
    float b0  = __shfl(zB[0], l15);
    float b1e = __shfl(zB[1], l15);
    float b2e = __shfl(zB[2], l15);
    float b3e = __shfl(zB[3], l15);

    const int  isB  = g >> 1;                 // lanes 32-63 handle subtile B
    const int  half = g & 1;
    const float lsum = isB ? lsB : lsA;
    const float z0 = isB ? b0 : a0;
    const float z1 = isB ? b1e : a1e;
    const float z2 = isB ? b2e : a2e;
    const float z3 = isB ? b3e : a3e;
    const int srow = rowA + (isB << 4);

    const float inv = 1.f / lsum;
    const float* wvp = Wv + h * 32 + half * 4;
    float4 o;
    o.x = inv * (z0 * wvp[0] + z1 * wvp[8]  + z2 * wvp[16] + z3 * wvp[24]);
    o.y = inv * (z0 * wvp[1] + z1 * wvp[9]  + z2 * wvp[17] + z3 * wvp[25]);
    o.z = inv * (z0 * wvp[2] + z1 * wvp[10] + z2 * wvp[18] + z3 * wvp[26]);
    o.w = inv * (z0 * wvp[3] + z1 * wvp[11] + z2 * wvp[19] + z3 * wvp[27]);
    float4* op = (float4*)(out + (size_t)(b * SEQ + srow) * (NH * 8) + h * 8 + half * 4);
    *op = o;
}

extern "C" void kernel_launch(void* const* d_in, const int* in_sizes, int n_in,
                              void* d_out, int out_size, void* d_ws, size_t ws_size,
                              hipStream_t stream) {
    const float* x  = (const float*)d_in[0];
    const float* Wq = (const float*)d_in[1];
    const float* Wk = (const float*)d_in[2];
    const float* Wv = (const float*)d_in[3];
    float* out = (float*)d_out;

    const int B = in_sizes[0] / (SEQ * 4);    // 4
    dim3 grid(B * NH * (SEQ / 128));          // 1024
    dim3 block(256);
    hipLaunchKernelGGL(mha_mfma_kernel, grid, block, 0, stream, x, Wq, Wk, Wv, out);
}

// Round 11
// 24.407 us; speedup vs baseline: 1.5454x; 1.5454x over previous
//
#include <hip/hip_runtime.h>
#include <hip/hip_bf16.h>
#include <math.h>

#define SEQ  1024
#define NH   32
#define XSTRIDE 1080   // shorts; 540 dwords ≡ 28 (mod 32) -> disjoint row bank-spans

typedef __attribute__((ext_vector_type(8))) short short8_t;
typedef __attribute__((ext_vector_type(4))) short short4_t;
typedef __attribute__((ext_vector_type(2))) short short2_t;
typedef __attribute__((ext_vector_type(4))) float float4_t;

__device__ inline float exp2_fast(float x) {
#if __has_builtin(__builtin_amdgcn_exp2f)
    return __builtin_amdgcn_exp2f(x);
#else
    return exp2f(x);
#endif
}

__device__ inline short f2bf(float f) {
    __hip_bfloat16 h = __float2bfloat16(f);
    return *reinterpret_cast<short*>(&h);
}

// Block = 256 threads = 4 waves; each wave owns 32 query rows (two 16-row
// subtiles A/B sharing all LDS reads). grid = B*NH*(SEQ/128) = 1024 blocks.
//
// scores^T[t,s] = sum_k x[t,k] * y'[s,k]  (K=4 padded to 32, bf16 MFMA)
//   y'[s] = (x_s Wq) Wk^T * (1/sqrt(8)) * log2(e)
// w = exp2(scores)   (no max subtraction: |score2| << 127, fp32 l can't overflow)
// Z^T[c,s] = sum_t XaugT[c,t] * w^T[t,s]  (Xaug rows: x0..x3, ones -> l, zeros)
// out[s, h*8+j] = (sum_c Z[c,s] Wv[c,j]) / Z[4,s]
//
// R11: revert to R8 exp path (trans pipe is cheaper than poly-VALU, proven
// R10); xT stride 1032 -> 1080 shorts to kill the 4-way bank collisions on
// the av ds_read_b128 (1.57M conflict cycles measured); unroll 8.
__global__ __launch_bounds__(256, 4) void mha_mfma_kernel(
    const float* __restrict__ x,    // [B, SEQ, 4]
    const float* __restrict__ Wq,   // [NH, 4, 8]
    const float* __restrict__ Wk,   // [NH, 4, 8]
    const float* __restrict__ Wv,   // [NH, 4, 8]
    float* __restrict__ out)        // [B, SEQ, NH*8]
{
    const int bid = blockIdx.x;
    const int rc  = bid & 7;            // row chunk (SEQ/128 = 8)
    const int h   = (bid >> 3) & 31;
    const int b   = bid >> 8;

    const int tid  = threadIdx.x;
    const int lane = tid & 63;
    const int wv   = tid >> 6;          // 0..3
    const int l15  = lane & 15;
    const int g    = lane >> 4;

    __shared__ short xbf[SEQ][4];        // 8 KB     row-major bf16 x
    __shared__ short xT[6][XSTRIDE];     // 12.7 KB  rows: x0..x3, ones, zeros

    // ---- stage ----
    const float4* xg = (const float4*)(x + (size_t)b * SEQ * 4);
    for (int i = tid; i < SEQ; i += 256) {
        float4 v = xg[i];
        short s0 = f2bf(v.x), s1 = f2bf(v.y), s2 = f2bf(v.z), s3 = f2bf(v.w);
        short4_t pk = {s0, s1, s2, s3};
        *(short4_t*)(&xbf[i][0]) = pk;
        xT[0][i] = s0; xT[1][i] = s1; xT[2][i] = s2; xT[3][i] = s3;
        xT[4][i] = (short)0x3F80;       // 1.0 bf16 (l-column)
        xT[5][i] = 0;                   // zero row (PV A rows >= 5)
    }

    // ---- per-lane y' for the two subtiles (B-frags of scores MFMA) ----
    const int rowA = rc * 128 + wv * 32 + l15;      // subtile A
    const int rowB = rowA + 16;                     // subtile B
    const float* wqp = Wq + h * 32;     // [4][8]
    const float* wkp = Wk + h * 32;
    const float cs = 0.35355339059327373f * 1.4426950408889634f; // 1/sqrt(8)*log2e

    float4 xsA = xg[rowA];
    float4 xsB = xg[rowB];
    float qA[8], qB[8];
#pragma unroll
    for (int m = 0; m < 8; ++m) {
        qA[m] = xsA.x * wqp[m] + xsA.y * wqp[8 + m] + xsA.z * wqp[16 + m] + xsA.w * wqp[24 + m];
        qB[m] = xsB.x * wqp[m] + xsB.y * wqp[8 + m] + xsB.z * wqp[16 + m] + xsB.w * wqp[24 + m];
    }
    short8_t yA = {0,0,0,0,0,0,0,0};
    short8_t yB = {0,0,0,0,0,0,0,0};
    if (lane < 16) {
#pragma unroll
        for (int i = 0; i < 4; ++i) {
            float ya = 0.f, yb = 0.f;
#pragma unroll
            for (int m = 0; m < 8; ++m) {
                ya += qA[m] * wkp[i * 8 + m];
                yb += qB[m] * wkp[i * 8 + m];
            }
            yA[i] = f2bf(ya * cs);
            yB[i] = f2bf(yb * cs);
        }
    }

    __syncthreads();

    // scores-A: ALL lanes read x rows t0 + f(l15), f = 8*(l>>2)+(l&3)
    // (lanes 16..63 duplicate lanes 0..15's addresses -> LDS broadcast)
    const short* abase = &xbf[8 * (l15 >> 2) + (l15 & 3)][0];
    // PV-A: row c = l15 (c>=5 -> zero row; their Z rows are ignored)
    const int rowm = (l15 < 5) ? l15 : 5;
    const short* vbase = &xT[rowm][8 * g];

    float4_t zA = {0.f, 0.f, 0.f, 0.f};
    float4_t zB = {0.f, 0.f, 0.f, 0.f};
    const float4_t cz = {0.f, 0.f, 0.f, 0.f};

    // loop-invariant zero high-halves for the scores A-frags
    const short2_t zpair = {0, 0};

#pragma unroll 8
    for (int it = 0; it < 32; ++it) {
        short4_t a1lo = *(const short4_t*)(abase + it * 128);        // rows f(l15)+32it
        short4_t a2lo = *(const short4_t*)(abase + it * 128 + 16);   // +4 rows
        short8_t a1 = {a1lo[0], a1lo[1], a1lo[2], a1lo[3],
                       zpair[0], zpair[1], zpair[0], zpair[1]};
        short8_t a2 = {a2lo[0], a2lo[1], a2lo[2], a2lo[3],
                       zpair[0], zpair[1], zpair[0], zpair[1]};
        short8_t av = *(const short8_t*)(vbase + it * 32);           // XaugT[c][32it+8g..]

        float4_t c1A = __builtin_amdgcn_mfma_f32_16x16x32_bf16(a1, yA, cz, 0, 0, 0);
        float4_t c2A = __builtin_amdgcn_mfma_f32_16x16x32_bf16(a2, yA, cz, 0, 0, 0);
        float4_t c1B = __builtin_amdgcn_mfma_f32_16x16x32_bf16(a1, yB, cz, 0, 0, 0);
        float4_t c2B = __builtin_amdgcn_mfma_f32_16x16x32_bf16(a2, yB, cz, 0, 0, 0);

        short8_t wfA, wfB;
#pragma unroll
        for (int i = 0; i < 4; ++i) {
            wfA[i]     = f2bf(exp2_fast(c1A[i]));
            wfA[4 + i] = f2bf(exp2_fast(c2A[i]));
            wfB[i]     = f2bf(exp2_fast(c1B[i]));
            wfB[4 + i] = f2bf(exp2_fast(c2B[i]));
        }

        zA = __builtin_amdgcn_mfma_f32_16x16x32_bf16(av, wfA, zA, 0, 0, 0);
        zB = __builtin_amdgcn_mfma_f32_16x16x32_bf16(av, wfB, zB, 0, 0, 0);
    }

    // ---- epilogue ----
    // C layout: col = lane&15 (s), row = 4*(lane>>4)+reg (c). Need c=0..3 and c=4 (=l).
    float lsA = __shfl(zA[0], 16 + l15);
    float a0  = __shfl(zA[0], l15);
    float a1e = __shfl(zA[1], l15);
    float a2e = __shfl(zA[2], l15);
    float a3e = __shfl(zA[3], l15);
    float lsB = __shfl(zB[0], 16 + l15);
    float b0  = __shfl(zB[0], l15);
    float b1e = __shfl(zB[1], l15);
    float b2e = __shfl(zB[2], l15);
    float b3e = __shfl(zB[3], l15);

    const int  isB  = g >> 1;                 // lanes 32-63 handle subtile B
    const int  half = g & 1;
    const float lsum = isB ? lsB : lsA;
    const float z0 = isB ? b0 : a0;
    const float z1 = isB ? b1e : a1e;
    const float z2 = isB ? b2e : a2e;
    const float z3 = isB ? b3e : a3e;
    const int srow = rowA + (isB << 4);

    const float inv = 1.f / lsum;
    const float* wvp = Wv + h * 32 + half * 4;
    float4 o;
    o.x = inv * (z0 * wvp[0] + z1 * wvp[8]  + z2 * wvp[16] + z3 * wvp[24]);
    o.y = inv * (z0 * wvp[1] + z1 * wvp[9]  + z2 * wvp[17] + z3 * wvp[25]);
    o.z = inv * (z0 * wvp[2] + z1 * wvp[10] + z2 * wvp[18] + z3 * wvp[26]);
    o.w = inv * (z0 * wvp[3] + z1 * wvp[11] + z2 * wvp[19] + z3 * wvp[27]);
    float4* op = (float4*)(out + (size_t)(b * SEQ + srow) * (NH * 8) + h * 8 + half * 4);
    *op = o;
}

extern "C" void kernel_launch(void* const* d_in, const int* in_sizes, int n_in,
                              void* d_out, int out_size, void* d_ws, size_t ws_size,
                              hipStream_t stream) {
    const float* x  = (const float*)d_in[0];
    const float* Wq = (const float*)d_in[1];
    const float* Wk = (const float*)d_in[2];
    const float* Wv = (const float*)d_in[3];
    float* out = (float*)d_out;

    const int B = in_sizes[0] / (SEQ * 4);    // 4
    dim3 grid(B * NH * (SEQ / 128));          // 1024
    dim3 block(256);
    hipLaunchKernelGGL(mha_mfma_kernel, grid, block, 0, stream, x, Wq, Wk, Wv, out);
}